// Round 3
// baseline (513.065 us; speedup 1.0000x reference)
//
#include <hip/hip_runtime.h>
#include <math.h>

// Problem constants
#define B   32
#define TU  128
#define TM  128
#define TZ  32
#define TENC 288
#define V   10000
#define H   512
#define E   128
#define S   640          // E + H
#define G3  1536         // 3*H
#define NLOG (V + TENC)  // 10288

// Workspace float region (float offsets)
#define WS_Q      0                       // B*H
#define WS_SCORE  (WS_Q + B*H)            // B*TENC
#define WS_CTX    (WS_SCORE + B*TENC)     // B*H
#define WS_GI     (WS_CTX + B*H)          // B*G3
#define WS_GH     (WS_GI + B*G3)          // B*G3
#define WS_ST     (WS_GH + B*G3)          // B*S
#define WS_LOGIT  (WS_ST + B*S)           // B*NLOG
#define WS_PCOPY  (WS_LOGIT + B*NLOG)     // B*TENC
#define WS_F_TOTAL (WS_PCOPY + B*TENC)    // 499200 floats (16B-aligned)

// bf16 (ushort) region, offsets from bf = (ushort*)(ws + WS_F_TOTAL).
#define BF_WA2  0                         // W_attn[:,H:] 16 tiles x 512 x 32
#define BF_WCP  (BF_WA2 + 512*512)        // 3 segs, each 16 tiles x 640 x 32
#define BF_ENC  (BF_WCP + 3*640*512)      // [b][k/32][t 288][32]
#define BF_ST   (BF_ENC + B*TENC*H)       // [b][s 640]
#define BF_TANH (BF_ST + B*S)             // [b][t 288][s 640] tanh(enc·Wcp+b)

typedef __attribute__((ext_vector_type(8))) short bf16x8_t;
typedef __attribute__((ext_vector_type(4))) float f32x4_t;
typedef __attribute__((ext_vector_type(16))) float f32x16_t;

__device__ __forceinline__ float fast_tanh(float x) {
    return 1.f - 2.f / (__expf(2.f * x) + 1.f);
}

__device__ __forceinline__ unsigned short f2bf(float x) {
    unsigned int u = __float_as_uint(x);
    u += 0x7fffu + ((u >> 16) & 1u);   // RNE
    return (unsigned short)(u >> 16);
}

__device__ __forceinline__ float bf2f(unsigned short u) {
    return __uint_as_float(((unsigned int)u) << 16);
}

__device__ __forceinline__ bf16x8_t cvt8(const float* p) {
    float4 a = *(const float4*)(p);
    float4 b = *(const float4*)(p + 4);
    bf16x8_t r;
    r[0] = (short)f2bf(a.x); r[1] = (short)f2bf(a.y);
    r[2] = (short)f2bf(a.z); r[3] = (short)f2bf(a.w);
    r[4] = (short)f2bf(b.x); r[5] = (short)f2bf(b.y);
    r[6] = (short)f2bf(b.z); r[7] = (short)f2bf(b.w);
    return r;
}

__device__ __forceinline__ const float* enc_row(const float* u, const float* m,
                                                const float* pz, int b, int t) {
    if (t < TU) return u + ((size_t)b * TU + t) * H;
    if (t < TU + TM) return m + ((size_t)b * TM + (t - TU)) * H;
    return pz + ((size_t)b * TZ + (t - TU - TM)) * H;
}

// ---------------- K0: prep = matvec(q, gh, gi_emb) + all cvt ---------------
// Blocks [0,112): 4-wave k-split MFMA matvecs (each wave a K-quarter, LDS
// reduce). Blocks [112, 112+5824): weight+enc bf16 cvt with k-tile swizzle.
#define CVT_WA2_END  65536                      // 512 g x 128 float4 units
#define CVT_TOTAL    (CVT_WA2_END + 3*81920)    // 311296
#define CVTE_TOTAL   (B * TENC * 128)           // 1179648 float4 units
#define CVT_ALL      (CVT_TOTAL + CVTE_TOTAL)
#define NMV          112
__global__ __launch_bounds__(256) void k_prep(const float* __restrict__ W_attn,
                                              const float* __restrict__ W_cpu,
                                              const float* __restrict__ W_cpm,
                                              const float* __restrict__ W_cppz,
                                              const float* __restrict__ u_h,
                                              const float* __restrict__ m_h,
                                              const float* __restrict__ pz_h,
                                              const float* __restrict__ last_h,
                                              const float* __restrict__ emb,
                                              const float* __restrict__ W_hh,
                                              const float* __restrict__ W_ih,
                                              const float* __restrict__ b_attn,
                                              const float* __restrict__ b_hh,
                                              const float* __restrict__ b_ih,
                                              float* __restrict__ ws,
                                              unsigned short* __restrict__ bf) {
    int blk = blockIdx.x, tid = threadIdx.x;
    __shared__ float redmv[4][64][16];          // 16 KB
    if (blk < NMV) {
        int wave = tid >> 6, lane = tid & 63;
        int m = lane & 31, khalf = lane >> 5;
        f32x16_t acc = {};
        int n;
        if (blk < 16) {                         // q: K=512
            n = blk * 32 + m;
            const float* aptr = last_h + (size_t)m * H + khalf * 8;
            const float* bptr = W_attn + (size_t)n * 1024 + khalf * 8;
            for (int k0 = wave * 128; k0 < wave * 128 + 128; k0 += 16)
                acc = __builtin_amdgcn_mfma_f32_32x32x16_bf16(cvt8(aptr + k0),
                                                              cvt8(bptr + k0), acc, 0, 0, 0);
        } else if (blk < 64) {                  // gh: K=512
            n = (blk - 16) * 32 + m;
            const float* aptr = last_h + (size_t)m * H + khalf * 8;
            const float* bptr = W_hh + (size_t)n * H + khalf * 8;
            for (int k0 = wave * 128; k0 < wave * 128 + 128; k0 += 16)
                acc = __builtin_amdgcn_mfma_f32_32x32x16_bf16(cvt8(aptr + k0),
                                                              cvt8(bptr + k0), acc, 0, 0, 0);
        } else {                                // gi emb-part: K=128
            n = (blk - 64) * 32 + m;
            const float* aptr = emb + (size_t)m * E + khalf * 8;
            const float* bptr = W_ih + (size_t)n * S + khalf * 8;
            for (int k0 = wave * 32; k0 < wave * 32 + 32; k0 += 16)
                acc = __builtin_amdgcn_mfma_f32_32x32x16_bf16(cvt8(aptr + k0),
                                                              cvt8(bptr + k0), acc, 0, 0, 0);
        }
#pragma unroll
        for (int r = 0; r < 16; ++r) redmv[wave][lane][r] = acc[r];
        __syncthreads();
        if (wave == 0) {
#pragma unroll
            for (int r = 0; r < 16; ++r) {
                float v = redmv[0][lane][r] + redmv[1][lane][r] +
                          redmv[2][lane][r] + redmv[3][lane][r];
                int row = (r & 3) + 8 * (r >> 2) + 4 * khalf;   // b index
                if (blk < 16)      ws[WS_Q  + row * H  + n] = v + b_attn[n];
                else if (blk < 64) ws[WS_GH + row * G3 + n] = v + b_hh[n];
                else               ws[WS_GI + row * G3 + n] = v + b_ih[n];
            }
        }
        return;
    }
    int idx = (blk - NMV) * 256 + tid;
    if (idx >= CVT_ALL) return;
    const float* src;
    unsigned short* dst;
    if (idx < CVT_WA2_END) {
        int g = idx >> 7, c4 = idx & 127;
        int k = c4 * 4, kt = k >> 5, kin = k & 31;
        src = W_attn + (size_t)g * 1024 + 512 + k;
        dst = bf + BF_WA2 + kt * (512 * 32) + g * 32 + kin;
    } else if (idx < CVT_TOTAL) {
        int r = idx - CVT_WA2_END;
        int seg = r / 81920, q = r % 81920;
        int s = q >> 7, c4 = q & 127;
        int k = c4 * 4, kt = k >> 5, kin = k & 31;
        const float* s0 = (seg == 0) ? W_cpu : (seg == 1) ? W_cpm : W_cppz;
        src = s0 + (size_t)s * 512 + k;
        dst = bf + BF_WCP + seg * 327680 + kt * (640 * 32) + s * 32 + kin;
    } else {
        int e = idx - CVT_TOTAL;
        int b = e / (TENC * 128);
        int r = e % (TENC * 128);
        int t = r >> 7, c4 = r & 127;
        int k = c4 * 4, kt = k >> 5, kin = k & 31;
        src = enc_row(u_h, m_h, pz_h, b, t) + k;
        dst = bf + BF_ENC + (((size_t)b * 16 + kt) * TENC + t) * 32 + kin;
    }
    float4 v = *(const float4*)src;
    ushort4 o;
    o.x = f2bf(v.x); o.y = f2bf(v.y); o.z = f2bf(v.z); o.w = f2bf(v.w);
    *(ushort4*)dst = o;
}

// ---------------- K1: enc MFMA, split into attn / copy 4-wave blocks -------
// 576 blocks (288 A-type + 288 C-type) instead of 288 8-wave blocks: kills
// the 288-on-256-CU tail (was ~44% waste) and raises blocks/CU co-residency.
__global__ __launch_bounds__(256) void k_enc_mfma(const unsigned short* __restrict__ bf,
                                                  const float* __restrict__ v_attn,
                                                  const float* __restrict__ b_cpu,
                                                  const float* __restrict__ b_cpm,
                                                  const float* __restrict__ b_cppz,
                                                  float* __restrict__ ws,
                                                  unsigned short* __restrict__ bft) {
    int blk = blockIdx.x;
    int typeC = blk & 1;
    int idx = blk >> 1;
    int b = idx / 9, t0 = (idx % 9) * 32;            // 9*32 = 288 = TENC
    int tid = threadIdx.x, wave = tid >> 6, lane = tid & 63;
    int n16 = lane & 15, quad = lane >> 4;
    const unsigned short* abase =
        bf + BF_ENC + (((size_t)b * 16) * TENC + t0 + n16) * 32 + quad * 8;
    if (!typeC) {
        // ---- attn: 512 cols, 8 groups/wave ----
        const unsigned short* wa =
            bf + BF_WA2 + (wave * 8) * (16 * 32) + n16 * 32 + quad * 8;
        f32x4_t acc[2][8];
#pragma unroll
        for (int tl = 0; tl < 2; ++tl)
#pragma unroll
            for (int j = 0; j < 8; ++j) acc[tl][j] = (f32x4_t){0.f, 0.f, 0.f, 0.f};
        for (int kt = 0; kt < 16; ++kt) {
            bf16x8_t a0 = *(const bf16x8_t*)(abase + (size_t)kt * TENC * 32);
            bf16x8_t a1 = *(const bf16x8_t*)(abase + (size_t)kt * TENC * 32 + 16 * 32);
            const unsigned short* wak = wa + (size_t)kt * 512 * 32;
#pragma unroll
            for (int j = 0; j < 8; ++j) {
                bf16x8_t bb = *(const bf16x8_t*)(wak + j * (16 * 32));
                acc[0][j] = __builtin_amdgcn_mfma_f32_16x16x32_bf16(a0, bb, acc[0][j], 0, 0, 0);
                acc[1][j] = __builtin_amdgcn_mfma_f32_16x16x32_bf16(a1, bb, acc[1][j], 0, 0, 0);
            }
        }
        float sval[2][4] = {{0.f, 0.f, 0.f, 0.f}, {0.f, 0.f, 0.f, 0.f}};
#pragma unroll
        for (int j = 0; j < 8; ++j) {
            int g = (wave * 8 + j) * 16 + n16;
            float q = ws[WS_Q + b * H + g];
            float va = v_attn[g];
#pragma unroll
            for (int tl = 0; tl < 2; ++tl)
#pragma unroll
                for (int r = 0; r < 4; ++r)
                    sval[tl][r] += fast_tanh(acc[tl][j][r] + q) * va;
        }
#pragma unroll
        for (int tl = 0; tl < 2; ++tl)
#pragma unroll
            for (int r = 0; r < 4; ++r)
#pragma unroll
                for (int off = 8; off > 0; off >>= 1)
                    sval[tl][r] += __shfl_down(sval[tl][r], off, 64);
        __shared__ float red[4][32];
        if (n16 == 0)
#pragma unroll
            for (int tl = 0; tl < 2; ++tl)
#pragma unroll
                for (int r = 0; r < 4; ++r)
                    red[wave][tl * 16 + quad * 4 + r] = sval[tl][r];
        __syncthreads();
        if (tid < 32)
            ws[WS_SCORE + b * TENC + t0 + tid] =
                red[0][tid] + red[1][tid] + red[2][tid] + red[3][tid];
    } else {
        // ---- copy: 640 cols, 10 groups/wave ----
        int seg = (t0 < TU) ? 0 : (t0 < TU + TM) ? 1 : 2;
        const float* bias = (seg == 0) ? b_cpu : (seg == 1) ? b_cpm : b_cppz;
        const unsigned short* wc =
            bf + BF_WCP + seg * 327680 + (wave * 10) * (16 * 32) + n16 * 32 + quad * 8;
        f32x4_t acc[2][10];
#pragma unroll
        for (int tl = 0; tl < 2; ++tl)
#pragma unroll
            for (int j = 0; j < 10; ++j) acc[tl][j] = (f32x4_t){0.f, 0.f, 0.f, 0.f};
        for (int kt = 0; kt < 16; ++kt) {
            bf16x8_t a0 = *(const bf16x8_t*)(abase + (size_t)kt * TENC * 32);
            bf16x8_t a1 = *(const bf16x8_t*)(abase + (size_t)kt * TENC * 32 + 16 * 32);
            const unsigned short* wck = wc + (size_t)kt * 640 * 32;
#pragma unroll
            for (int j = 0; j < 10; ++j) {
                bf16x8_t bb = *(const bf16x8_t*)(wck + j * (16 * 32));
                acc[0][j] = __builtin_amdgcn_mfma_f32_16x16x32_bf16(a0, bb, acc[0][j], 0, 0, 0);
                acc[1][j] = __builtin_amdgcn_mfma_f32_16x16x32_bf16(a1, bb, acc[1][j], 0, 0, 0);
            }
        }
#pragma unroll
        for (int j = 0; j < 10; ++j) {
            int s = (wave * 10 + j) * 16 + n16;
            float bi = bias[s];
#pragma unroll
            for (int tl = 0; tl < 2; ++tl)
#pragma unroll
                for (int r = 0; r < 4; ++r) {
                    int t = t0 + tl * 16 + quad * 4 + r;
                    bft[BF_TANH + ((size_t)b * TENC + t) * S + s] =
                        f2bf(fast_tanh(acc[tl][j][r] + bi));
                }
        }
    }
}

// ---------------- K2: softmax over t and context (ushort2, 2 h/thread) -----
__global__ __launch_bounds__(256) void k_softmax_ctx(const unsigned short* __restrict__ bf,
                                                     float* __restrict__ ws) {
    int b = blockIdx.x, tid = threadIdx.x;
    __shared__ float wsm[TENC];
    __shared__ float red1[4], red2[4];
    float local = -1e30f;
    for (int t = tid; t < TENC; t += 256) {
        float s = ws[WS_SCORE + b * TENC + t];
        wsm[t] = s;
        local = fmaxf(local, s);
    }
    int lane = tid & 63, wv = tid >> 6;
    for (int off = 32; off > 0; off >>= 1) local = fmaxf(local, __shfl_down(local, off, 64));
    if (lane == 0) red1[wv] = local;
    __syncthreads();
    float mx = fmaxf(fmaxf(red1[0], red1[1]), fmaxf(red1[2], red1[3]));
    float ls = 0.f;
    for (int t = tid; t < TENC; t += 256) {
        float e = __expf(wsm[t] - mx);
        wsm[t] = e;
        ls += e;
    }
    for (int off = 32; off > 0; off >>= 1) ls += __shfl_down(ls, off, 64);
    if (lane == 0) red2[wv] = ls;
    __syncthreads();
    float inv = 1.f / (red2[0] + red2[1] + red2[2] + red2[3]);

    int h2 = tid * 2;
    int kt = h2 >> 5, hin = h2 & 31;
    const unsigned short* ep = bf + BF_ENC + ((size_t)b * 16 + kt) * TENC * 32 + hin;
    float a00 = 0.f, a01 = 0.f, a10 = 0.f, a11 = 0.f;
#pragma unroll 2
    for (int t = 0; t < TENC; t += 2) {
        ushort2 v0 = *(const ushort2*)(ep + (size_t)t * 32);
        ushort2 v1 = *(const ushort2*)(ep + (size_t)(t + 1) * 32);
        float w0 = wsm[t], w1 = wsm[t + 1];
        a00 += w0 * bf2f(v0.x); a10 += w0 * bf2f(v0.y);
        a01 += w1 * bf2f(v1.x); a11 += w1 * bf2f(v1.y);
    }
    ws[WS_CTX + b * H + h2]     = (a00 + a01) * inv;
    ws[WS_CTX + b * H + h2 + 1] = (a10 + a11) * inv;
}

// ---------------- K3: gi += ctx · W_ih[:, E:]^T  (4-wave k-split) ----------
__global__ __launch_bounds__(256) void k_gru_ctx(const float* __restrict__ W_ih,
                                                 float* __restrict__ ws) {
    int blk = blockIdx.x, tid = threadIdx.x;
    __shared__ float redmv[4][64][16];
    int wave = tid >> 6, lane = tid & 63;
    int m = lane & 31, khalf = lane >> 5;
    int n = blk * 32 + m;
    const float* aptr = ws + WS_CTX + (size_t)m * H + khalf * 8;
    const float* bptr = W_ih + (size_t)n * S + E + khalf * 8;
    f32x16_t acc = {};
    for (int k0 = wave * 128; k0 < wave * 128 + 128; k0 += 16)
        acc = __builtin_amdgcn_mfma_f32_32x32x16_bf16(cvt8(aptr + k0),
                                                      cvt8(bptr + k0), acc, 0, 0, 0);
#pragma unroll
    for (int r = 0; r < 16; ++r) redmv[wave][lane][r] = acc[r];
    __syncthreads();
    if (wave == 0) {
#pragma unroll
        for (int r = 0; r < 16; ++r) {
            float v = redmv[0][lane][r] + redmv[1][lane][r] +
                      redmv[2][lane][r] + redmv[3][lane][r];
            int row = (r & 3) + 8 * (r >> 2) + 4 * khalf;
            ws[WS_GI + row * G3 + n] += v;
        }
    }
}

// ---------------- K4: GRU pointwise; emits fp32 st and bf16 st -------------
__global__ __launch_bounds__(256) void k_combine(const float* __restrict__ emb,
                                                 const float* __restrict__ last_hidden,
                                                 float* __restrict__ ws,
                                                 unsigned short* __restrict__ bf,
                                                 float* __restrict__ out) {
    int i = blockIdx.x * 256 + threadIdx.x;
    int b = i >> 9, h = i & 511;
    float gi_r = ws[WS_GI + b * G3 + h];
    float gi_z = ws[WS_GI + b * G3 + H + h];
    float gi_n = ws[WS_GI + b * G3 + 2 * H + h];
    float gh_r = ws[WS_GH + b * G3 + h];
    float gh_z = ws[WS_GH + b * G3 + H + h];
    float gh_n = ws[WS_GH + b * G3 + 2 * H + h];
    float rr = 1.f / (1.f + __expf(-(gi_r + gh_r)));
    float zz = 1.f / (1.f + __expf(-(gi_z + gh_z)));
    float nn = fast_tanh(gi_n + rr * gh_n);
    float hp = last_hidden[b * H + h];
    float hn = (1.f - zz) * nn + zz * hp;
    out[V * B + b * H + h] = hn;
    out[V * B + B * H + b * H + h] = hn;
    ws[WS_ST + b * S + h] = hn;
    bf[BF_ST + b * S + h] = f2bf(hn);
    if (h < E) {
        float ev = emb[b * E + h];
        ws[WS_ST + b * S + H + h] = ev;
        bf[BF_ST + b * S + H + h] = f2bf(ev);
    }
}

// ---------------- K5: logits = copy-reduce (blk<576) + score_g (k-split) ---
__global__ __launch_bounds__(256) void k_logits(const unsigned short* __restrict__ bf,
                                                const float* __restrict__ W_gen,
                                                const float* __restrict__ b_gen,
                                                float* __restrict__ ws) {
    int blk = blockIdx.x, tid = threadIdx.x;
    __shared__ float shmem[4 * 64 * 16];        // 16 KB (st_s uses first 640)
    int wave = tid >> 6, lane = tid & 63;
    if (blk < 576) {
        // copy scores: tanh-matrix · st
        int b = blk / 18, t0 = (blk % 18) * 16;
        float* st_s = shmem;
        for (int i = tid; i < S; i += 256) st_s[i] = ws[WS_ST + b * S + i];
        __syncthreads();
#pragma unroll
        for (int tl = 0; tl < 4; ++tl) {
            int t = t0 + wave * 4 + tl;
            const unsigned short* row = bf + BF_TANH + ((size_t)b * TENC + t) * S;
            float acc = 0.f;
#pragma unroll
            for (int i = 0; i < 10; ++i) {
                int s = lane + 64 * i;
                acc += bf2f(row[s]) * st_s[s];
            }
            for (int off = 32; off > 0; off >>= 1) acc += __shfl_down(acc, off, 64);
            if (lane == 0) ws[WS_LOGIT + (size_t)b * NLOG + V + t] = acc;
        }
    } else {
        // score_g: st · W_gen^T, 4-wave k-split (K=640, 160/wave)
        float (*redmv)[64][16] = (float (*)[64][16])shmem;
        int m = lane & 31, khalf = lane >> 5;
        int n = (blk - 576) * 32 + m;
        int nr = (n < V) ? n : (V - 1);
        const unsigned short* aptr = bf + BF_ST + (size_t)m * S + khalf * 8;
        const float* bptr = W_gen + (size_t)nr * S + khalf * 8;
        f32x16_t acc = {};
        for (int k0 = wave * 160; k0 < wave * 160 + 160; k0 += 16)
            acc = __builtin_amdgcn_mfma_f32_32x32x16_bf16(*(const bf16x8_t*)(aptr + k0),
                                                          cvt8(bptr + k0), acc, 0, 0, 0);
#pragma unroll
        for (int r = 0; r < 16; ++r) redmv[wave][lane][r] = acc[r];
        __syncthreads();
        if (wave == 0 && n < V) {
            float bg = b_gen[n];
#pragma unroll
            for (int r = 0; r < 16; ++r) {
                float v = redmv[0][lane][r] + redmv[1][lane][r] +
                          redmv[2][lane][r] + redmv[3][lane][r];
                int row = (r & 3) + 8 * (r >> 2) + 4 * khalf;
                ws[WS_LOGIT + (size_t)row * NLOG + n] = v + bg;
            }
        }
    }
}

// ---------------- K6: final softmax + one-hot scatter (LDS exp cache) ------
__global__ __launch_bounds__(512) void k_softmax_scatter(const int* __restrict__ u_in,
                                                         const int* __restrict__ m_in,
                                                         float* __restrict__ ws,
                                                         float* __restrict__ out) {
    int b = blockIdx.x, tid = threadIdx.x;
    __shared__ float red1[8], red2[8];
    __shared__ float ex[NLOG];          // 41.2 KB: single global read of logits
    const float* lg = ws + WS_LOGIT + (size_t)b * NLOG;
    float mx = -1e30f;
    for (int i = tid; i < NLOG; i += 512) {
        float v = lg[i];
        ex[i] = v;
        mx = fmaxf(mx, v);
    }
    int lane = tid & 63, wv = tid >> 6;
    for (int off = 32; off > 0; off >>= 1) mx = fmaxf(mx, __shfl_down(mx, off, 64));
    if (lane == 0) red1[wv] = mx;
    __syncthreads();
    mx = red1[0];
#pragma unroll
    for (int w = 1; w < 8; ++w) mx = fmaxf(mx, red1[w]);
    float sm = 0.f;
    for (int i = tid; i < NLOG; i += 512) {
        float e = __expf(ex[i] - mx);
        ex[i] = e;
        sm += e;
    }
    for (int off = 32; off > 0; off >>= 1) sm += __shfl_down(sm, off, 64);
    if (lane == 0) red2[wv] = sm;
    __syncthreads();
    sm = red2[0];
#pragma unroll
    for (int w = 1; w < 8; ++w) sm += red2[w];
    float inv = 1.f / sm;
    for (int i = tid; i < V; i += 512) out[b * V + i] = ex[i] * inv;
    __syncthreads();
    if (tid < TU + TM) {
        int idx = (tid < TU) ? u_in[b * TU + tid] : m_in[b * TM + (tid - TU)];
        atomicAdd(&out[(size_t)b * V + idx], ex[V + tid] * inv);
    } else if (tid < TENC) {
        ws[WS_PCOPY + b * TENC + tid] = ex[V + tid] * inv;   // TZ slice for k_pv
    }
}

// ---------------- K7: dense pv_z_prob accumulation -------------------------
__global__ __launch_bounds__(256) void k_pv(const float* __restrict__ pvp,
                                            const float* __restrict__ ws,
                                            float* __restrict__ out) {
    int b = blockIdx.y;
    int v = blockIdx.x * 256 + threadIdx.x;
    __shared__ float p[TZ];
    if (threadIdx.x < TZ) p[threadIdx.x] = ws[WS_PCOPY + b * TENC + TU + TM + threadIdx.x];
    __syncthreads();
    if (v >= V) return;
    float acc = 0.f;
#pragma unroll 4
    for (int t = 0; t < TZ; ++t) acc += p[t] * pvp[((size_t)b * TZ + t) * V + v];
    out[(size_t)b * V + v] += acc;
}

extern "C" void kernel_launch(void* const* d_in, const int* in_sizes, int n_in,
                              void* d_out, int out_size, void* d_ws, size_t ws_size,
                              hipStream_t stream) {
    const int*   u_input   = (const int*)d_in[0];
    const float* u_h       = (const float*)d_in[2];
    const int*   m_input   = (const int*)d_in[3];
    const float* m_h       = (const float*)d_in[5];
    const float* pv_prob   = (const float*)d_in[6];
    const float* pz_h      = (const float*)d_in[7];
    const float* emb       = (const float*)d_in[9];
    const float* last_h    = (const float*)d_in[10];
    const float* W_attn    = (const float*)d_in[11];
    const float* b_attn    = (const float*)d_in[12];
    const float* v_attn    = (const float*)d_in[13];
    const float* W_ih      = (const float*)d_in[14];
    const float* W_hh      = (const float*)d_in[15];
    const float* b_ih      = (const float*)d_in[16];
    const float* b_hh      = (const float*)d_in[17];
    const float* W_gen     = (const float*)d_in[18];
    const float* b_gen     = (const float*)d_in[19];
    const float* W_cpu     = (const float*)d_in[20];
    const float* b_cpu     = (const float*)d_in[21];
    const float* W_cpm     = (const float*)d_in[22];
    const float* b_cpm     = (const float*)d_in[23];
    const float* W_cppz    = (const float*)d_in[24];
    const float* b_cppz    = (const float*)d_in[25];
    float* ws  = (float*)d_ws;
    unsigned short* bf = (unsigned short*)(ws + WS_F_TOTAL);
    float* out = (float*)d_out;

    hipLaunchKernelGGL(k_prep, dim3(NMV + CVT_ALL / 256), dim3(256), 0, stream,
                       W_attn, W_cpu, W_cpm, W_cppz, u_h, m_h, pz_h,
                       last_h, emb, W_hh, W_ih, b_attn, b_hh, b_ih, ws, bf);
    hipLaunchKernelGGL(k_enc_mfma, dim3(576), dim3(256), 0, stream,
                       bf, v_attn, b_cpu, b_cpm, b_cppz, ws, bf);
    hipLaunchKernelGGL(k_softmax_ctx, dim3(B), dim3(256), 0, stream, bf, ws);
    hipLaunchKernelGGL(k_gru_ctx, dim3(48), dim3(256), 0, stream, W_ih, ws);
    hipLaunchKernelGGL(k_combine, dim3(64), dim3(256), 0, stream, emb, last_h, ws, bf, out);
    hipLaunchKernelGGL(k_logits, dim3(576 + 313), dim3(256), 0, stream, bf, W_gen, b_gen, ws);
    hipLaunchKernelGGL(k_softmax_scatter, dim3(B), dim3(512), 0, stream,
                       u_input, m_input, ws, out);
    hipLaunchKernelGGL(k_pv, dim3(40, B), dim3(256), 0, stream, pv_prob, ws, out);
}

// Round 4
// 468.101 us; speedup vs baseline: 1.0961x; 1.0961x over previous
//
#include <hip/hip_runtime.h>
#include <math.h>

// Problem constants
#define B   32
#define TU  128
#define TM  128
#define TZ  32
#define TENC 288
#define V   10000
#define H   512
#define E   128
#define S   640          // E + H
#define G3  1536         // 3*H
#define NLOG (V + TENC)  // 10288

// Workspace float region (float offsets)
#define WS_Q      0                       // B*H
#define WS_SCORE  (WS_Q + B*H)            // B*TENC
#define WS_CTX    (WS_SCORE + B*TENC)     // B*H
#define WS_GI     (WS_CTX + B*H)          // B*G3
#define WS_GH     (WS_GI + B*G3)          // B*G3
#define WS_ST     (WS_GH + B*G3)          // B*S
#define WS_LOGIT  (WS_ST + B*S)           // B*NLOG
#define WS_PCOPY  (WS_LOGIT + B*NLOG)     // B*TENC
#define WS_F_TOTAL (WS_PCOPY + B*TENC)    // 499200 floats (16B-aligned)

// bf16 (ushort) region, offsets from bf = (ushort*)(ws + WS_F_TOTAL).
#define BF_WA2  0                         // W_attn[:,H:] 16 tiles x 512 x 32
#define BF_WCP  (BF_WA2 + 512*512)        // 3 segs, each 16 tiles x 640 x 32
#define BF_ENC  (BF_WCP + 3*640*512)      // [b][k/32][t 288][32]
#define BF_ST   (BF_ENC + B*TENC*H)       // [b][s 640]
#define BF_TANH (BF_ST + B*S)             // [b][t 288][s 640] tanh(enc·Wcp+b)

typedef __attribute__((ext_vector_type(8))) short bf16x8_t;
typedef __attribute__((ext_vector_type(4))) float f32x4_t;
typedef __attribute__((ext_vector_type(16))) float f32x16_t;

__device__ __forceinline__ float fast_tanh(float x) {
    return 1.f - 2.f / (__expf(2.f * x) + 1.f);
}

__device__ __forceinline__ unsigned short f2bf(float x) {
    unsigned int u = __float_as_uint(x);
    u += 0x7fffu + ((u >> 16) & 1u);   // RNE
    return (unsigned short)(u >> 16);
}

__device__ __forceinline__ float bf2f(unsigned short u) {
    return __uint_as_float(((unsigned int)u) << 16);
}

__device__ __forceinline__ bf16x8_t cvt8(const float* p) {
    float4 a = *(const float4*)(p);
    float4 b = *(const float4*)(p + 4);
    bf16x8_t r;
    r[0] = (short)f2bf(a.x); r[1] = (short)f2bf(a.y);
    r[2] = (short)f2bf(a.z); r[3] = (short)f2bf(a.w);
    r[4] = (short)f2bf(b.x); r[5] = (short)f2bf(b.y);
    r[6] = (short)f2bf(b.z); r[7] = (short)f2bf(b.w);
    return r;
}

__device__ __forceinline__ const float* enc_row(const float* u, const float* m,
                                                const float* pz, int b, int t) {
    if (t < TU) return u + ((size_t)b * TU + t) * H;
    if (t < TU + TM) return m + ((size_t)b * TM + (t - TU)) * H;
    return pz + ((size_t)b * TZ + (t - TU - TM)) * H;
}

// ---------------- K0: prep = matvec(q, gh, gi_emb) + all cvt ---------------
#define CVT_WA2_END  65536                      // 512 g x 128 float4 units
#define CVT_TOTAL    (CVT_WA2_END + 3*81920)    // 311296
#define CVTE_TOTAL   (B * TENC * 128)           // 1179648 float4 units
#define CVT_ALL      (CVT_TOTAL + CVTE_TOTAL)
#define NMV          112
__global__ __launch_bounds__(256) void k_prep(const float* __restrict__ W_attn,
                                              const float* __restrict__ W_cpu,
                                              const float* __restrict__ W_cpm,
                                              const float* __restrict__ W_cppz,
                                              const float* __restrict__ u_h,
                                              const float* __restrict__ m_h,
                                              const float* __restrict__ pz_h,
                                              const float* __restrict__ last_h,
                                              const float* __restrict__ emb,
                                              const float* __restrict__ W_hh,
                                              const float* __restrict__ W_ih,
                                              const float* __restrict__ b_attn,
                                              const float* __restrict__ b_hh,
                                              const float* __restrict__ b_ih,
                                              float* __restrict__ ws,
                                              unsigned short* __restrict__ bf) {
    int blk = blockIdx.x, tid = threadIdx.x;
    __shared__ float redmv[4][64][16];          // 16 KB
    if (blk < NMV) {
        int wave = tid >> 6, lane = tid & 63;
        int m = lane & 31, khalf = lane >> 5;
        f32x16_t acc = {};
        int n;
        if (blk < 16) {                         // q: K=512
            n = blk * 32 + m;
            const float* aptr = last_h + (size_t)m * H + khalf * 8;
            const float* bptr = W_attn + (size_t)n * 1024 + khalf * 8;
            for (int k0 = wave * 128; k0 < wave * 128 + 128; k0 += 16)
                acc = __builtin_amdgcn_mfma_f32_32x32x16_bf16(cvt8(aptr + k0),
                                                              cvt8(bptr + k0), acc, 0, 0, 0);
        } else if (blk < 64) {                  // gh: K=512
            n = (blk - 16) * 32 + m;
            const float* aptr = last_h + (size_t)m * H + khalf * 8;
            const float* bptr = W_hh + (size_t)n * H + khalf * 8;
            for (int k0 = wave * 128; k0 < wave * 128 + 128; k0 += 16)
                acc = __builtin_amdgcn_mfma_f32_32x32x16_bf16(cvt8(aptr + k0),
                                                              cvt8(bptr + k0), acc, 0, 0, 0);
        } else {                                // gi emb-part: K=128
            n = (blk - 64) * 32 + m;
            const float* aptr = emb + (size_t)m * E + khalf * 8;
            const float* bptr = W_ih + (size_t)n * S + khalf * 8;
            for (int k0 = wave * 32; k0 < wave * 32 + 32; k0 += 16)
                acc = __builtin_amdgcn_mfma_f32_32x32x16_bf16(cvt8(aptr + k0),
                                                              cvt8(bptr + k0), acc, 0, 0, 0);
        }
#pragma unroll
        for (int r = 0; r < 16; ++r) redmv[wave][lane][r] = acc[r];
        __syncthreads();
        if (wave == 0) {
#pragma unroll
            for (int r = 0; r < 16; ++r) {
                float v = redmv[0][lane][r] + redmv[1][lane][r] +
                          redmv[2][lane][r] + redmv[3][lane][r];
                int row = (r & 3) + 8 * (r >> 2) + 4 * khalf;   // b index
                if (blk < 16)      ws[WS_Q  + row * H  + n] = v + b_attn[n];
                else if (blk < 64) ws[WS_GH + row * G3 + n] = v + b_hh[n];
                else               ws[WS_GI + row * G3 + n] = v + b_ih[n];
            }
        }
        return;
    }
    int idx = (blk - NMV) * 256 + tid;
    if (idx >= CVT_ALL) return;
    const float* src;
    unsigned short* dst;
    if (idx < CVT_WA2_END) {
        int g = idx >> 7, c4 = idx & 127;
        int k = c4 * 4, kt = k >> 5, kin = k & 31;
        src = W_attn + (size_t)g * 1024 + 512 + k;
        dst = bf + BF_WA2 + kt * (512 * 32) + g * 32 + kin;
    } else if (idx < CVT_TOTAL) {
        int r = idx - CVT_WA2_END;
        int seg = r / 81920, q = r % 81920;
        int s = q >> 7, c4 = q & 127;
        int k = c4 * 4, kt = k >> 5, kin = k & 31;
        const float* s0 = (seg == 0) ? W_cpu : (seg == 1) ? W_cpm : W_cppz;
        src = s0 + (size_t)s * 512 + k;
        dst = bf + BF_WCP + seg * 327680 + kt * (640 * 32) + s * 32 + kin;
    } else {
        int e = idx - CVT_TOTAL;
        int b = e / (TENC * 128);
        int r = e % (TENC * 128);
        int t = r >> 7, c4 = r & 127;
        int k = c4 * 4, kt = k >> 5, kin = k & 31;
        src = enc_row(u_h, m_h, pz_h, b, t) + k;
        dst = bf + BF_ENC + (((size_t)b * 16 + kt) * TENC + t) * 32 + kin;
    }
    float4 v = *(const float4*)src;
    ushort4 o;
    o.x = f2bf(v.x); o.y = f2bf(v.y); o.z = f2bf(v.z); o.w = f2bf(v.w);
    *(ushort4*)dst = o;
}

// ---------------- K1: enc MFMA with cooperative LDS staging ----------------
// blk<288: attn (512 cols), else copy (640 cols). Per kt: all 256 threads
// stage the weight k-tile (32/40 KB) + enc a-tile (2 KB) into LDS with
// batched INDEPENDENT global loads (one waitcnt), then waves ds_read
// fragments (short latency, no VGPR load buffers) and MFMA. This replaces
// the old serial per-fragment global-load->MFMA chain (VGPR-starved,
// ~250-900 cy per fragment) that made this kernel 99.7us latency-bound.
__global__ __launch_bounds__(256) void k_enc_mfma(const unsigned short* __restrict__ bf,
                                                  const float* __restrict__ v_attn,
                                                  const float* __restrict__ b_cpu,
                                                  const float* __restrict__ b_cpm,
                                                  const float* __restrict__ b_cppz,
                                                  float* __restrict__ ws,
                                                  unsigned short* __restrict__ bft) {
    __shared__ __attribute__((aligned(16))) unsigned short lds_w[640 * 32]; // 40 KB
    __shared__ __attribute__((aligned(16))) unsigned short lds_a[32 * 32];  // 2 KB
    __shared__ float red[4][32];
    int blk = blockIdx.x;
    int typeC = (blk >= 288);
    int idx = typeC ? blk - 288 : blk;
    int b = idx / 9, t0 = (idx % 9) * 32;            // 9*32 = 288 = TENC
    int tid = threadIdx.x, wave = tid >> 6, lane = tid & 63;
    int n16 = lane & 15, quad = lane >> 4;
    const unsigned short* asrc0 =
        bf + BF_ENC + (((size_t)b * 16) * TENC + t0) * 32;   // + kt*TENC*32
    if (!typeC) {
        // ---- attn: 512 cols, wave w owns groups w*8..w*8+7 ----
        f32x4_t acc[2][8];
#pragma unroll
        for (int tl = 0; tl < 2; ++tl)
#pragma unroll
            for (int j = 0; j < 8; ++j) acc[tl][j] = (f32x4_t){0.f, 0.f, 0.f, 0.f};
        for (int kt = 0; kt < 16; ++kt) {
            const unsigned short* wsrc = bf + BF_WA2 + (size_t)kt * (512 * 32);
            // stage: 512*32 ushorts = 2048 chunks of 16B; 8 per thread
#pragma unroll
            for (int c = 0; c < 8; ++c) {
                int u = (c * 256 + tid) * 8;
                *(bf16x8_t*)&lds_w[u] = *(const bf16x8_t*)&wsrc[u];
            }
            if (tid < 128) {
                int u = tid * 8;
                *(bf16x8_t*)&lds_a[u] =
                    *(const bf16x8_t*)&asrc0[(size_t)kt * TENC * 32 + u];
            }
            __syncthreads();
            bf16x8_t a0 = *(const bf16x8_t*)&lds_a[n16 * 32 + quad * 8];
            bf16x8_t a1 = *(const bf16x8_t*)&lds_a[(n16 + 16) * 32 + quad * 8];
#pragma unroll
            for (int j = 0; j < 8; ++j) {
                bf16x8_t bb = *(const bf16x8_t*)
                    &lds_w[((wave * 8 + j) * 16 + n16) * 32 + quad * 8];
                acc[0][j] = __builtin_amdgcn_mfma_f32_16x16x32_bf16(a0, bb, acc[0][j], 0, 0, 0);
                acc[1][j] = __builtin_amdgcn_mfma_f32_16x16x32_bf16(a1, bb, acc[1][j], 0, 0, 0);
            }
            __syncthreads();
        }
        float sval[2][4] = {{0.f, 0.f, 0.f, 0.f}, {0.f, 0.f, 0.f, 0.f}};
#pragma unroll
        for (int j = 0; j < 8; ++j) {
            int g = (wave * 8 + j) * 16 + n16;
            float q = ws[WS_Q + b * H + g];
            float va = v_attn[g];
#pragma unroll
            for (int tl = 0; tl < 2; ++tl)
#pragma unroll
                for (int r = 0; r < 4; ++r)
                    sval[tl][r] += fast_tanh(acc[tl][j][r] + q) * va;
        }
#pragma unroll
        for (int tl = 0; tl < 2; ++tl)
#pragma unroll
            for (int r = 0; r < 4; ++r)
#pragma unroll
                for (int off = 8; off > 0; off >>= 1)
                    sval[tl][r] += __shfl_down(sval[tl][r], off, 64);
        if (n16 == 0)
#pragma unroll
            for (int tl = 0; tl < 2; ++tl)
#pragma unroll
                for (int r = 0; r < 4; ++r)
                    red[wave][tl * 16 + quad * 4 + r] = sval[tl][r];
        __syncthreads();
        if (tid < 32)
            ws[WS_SCORE + b * TENC + t0 + tid] =
                red[0][tid] + red[1][tid] + red[2][tid] + red[3][tid];
    } else {
        // ---- copy: 640 cols, wave w owns groups w*10..w*10+9 ----
        int seg = (t0 < TU) ? 0 : (t0 < TU + TM) ? 1 : 2;
        const float* bias = (seg == 0) ? b_cpu : (seg == 1) ? b_cpm : b_cppz;
        f32x4_t acc[2][10];
#pragma unroll
        for (int tl = 0; tl < 2; ++tl)
#pragma unroll
            for (int j = 0; j < 10; ++j) acc[tl][j] = (f32x4_t){0.f, 0.f, 0.f, 0.f};
        for (int kt = 0; kt < 16; ++kt) {
            const unsigned short* wsrc =
                bf + BF_WCP + seg * 327680 + (size_t)kt * (640 * 32);
            // stage: 640*32 ushorts = 2560 chunks of 16B; 10 per thread
#pragma unroll
            for (int c = 0; c < 10; ++c) {
                int u = (c * 256 + tid) * 8;
                *(bf16x8_t*)&lds_w[u] = *(const bf16x8_t*)&wsrc[u];
            }
            if (tid < 128) {
                int u = tid * 8;
                *(bf16x8_t*)&lds_a[u] =
                    *(const bf16x8_t*)&asrc0[(size_t)kt * TENC * 32 + u];
            }
            __syncthreads();
            bf16x8_t a0 = *(const bf16x8_t*)&lds_a[n16 * 32 + quad * 8];
            bf16x8_t a1 = *(const bf16x8_t*)&lds_a[(n16 + 16) * 32 + quad * 8];
#pragma unroll
            for (int j = 0; j < 10; ++j) {
                bf16x8_t bb = *(const bf16x8_t*)
                    &lds_w[((wave * 10 + j) * 16 + n16) * 32 + quad * 8];
                acc[0][j] = __builtin_amdgcn_mfma_f32_16x16x32_bf16(a0, bb, acc[0][j], 0, 0, 0);
                acc[1][j] = __builtin_amdgcn_mfma_f32_16x16x32_bf16(a1, bb, acc[1][j], 0, 0, 0);
            }
            __syncthreads();
        }
#pragma unroll
        for (int j = 0; j < 10; ++j) {
            int s = (wave * 10 + j) * 16 + n16;
            float bi = bias[s];
#pragma unroll
            for (int tl = 0; tl < 2; ++tl)
#pragma unroll
                for (int r = 0; r < 4; ++r) {
                    int t = t0 + tl * 16 + quad * 4 + r;
                    bft[BF_TANH + ((size_t)b * TENC + t) * S + s] =
                        f2bf(fast_tanh(acc[tl][j][r] + bi));
                }
        }
    }
}

// ---------------- K2: softmax over t and context (ushort2, 2 h/thread) -----
__global__ __launch_bounds__(256) void k_softmax_ctx(const unsigned short* __restrict__ bf,
                                                     float* __restrict__ ws) {
    int b = blockIdx.x, tid = threadIdx.x;
    __shared__ float wsm[TENC];
    __shared__ float red1[4], red2[4];
    float local = -1e30f;
    for (int t = tid; t < TENC; t += 256) {
        float s = ws[WS_SCORE + b * TENC + t];
        wsm[t] = s;
        local = fmaxf(local, s);
    }
    int lane = tid & 63, wv = tid >> 6;
    for (int off = 32; off > 0; off >>= 1) local = fmaxf(local, __shfl_down(local, off, 64));
    if (lane == 0) red1[wv] = local;
    __syncthreads();
    float mx = fmaxf(fmaxf(red1[0], red1[1]), fmaxf(red1[2], red1[3]));
    float ls = 0.f;
    for (int t = tid; t < TENC; t += 256) {
        float e = __expf(wsm[t] - mx);
        wsm[t] = e;
        ls += e;
    }
    for (int off = 32; off > 0; off >>= 1) ls += __shfl_down(ls, off, 64);
    if (lane == 0) red2[wv] = ls;
    __syncthreads();
    float inv = 1.f / (red2[0] + red2[1] + red2[2] + red2[3]);

    int h2 = tid * 2;
    int kt = h2 >> 5, hin = h2 & 31;
    const unsigned short* ep = bf + BF_ENC + ((size_t)b * 16 + kt) * TENC * 32 + hin;
    float a00 = 0.f, a01 = 0.f, a10 = 0.f, a11 = 0.f;
#pragma unroll 2
    for (int t = 0; t < TENC; t += 2) {
        ushort2 v0 = *(const ushort2*)(ep + (size_t)t * 32);
        ushort2 v1 = *(const ushort2*)(ep + (size_t)(t + 1) * 32);
        float w0 = wsm[t], w1 = wsm[t + 1];
        a00 += w0 * bf2f(v0.x); a10 += w0 * bf2f(v0.y);
        a01 += w1 * bf2f(v1.x); a11 += w1 * bf2f(v1.y);
    }
    ws[WS_CTX + b * H + h2]     = (a00 + a01) * inv;
    ws[WS_CTX + b * H + h2 + 1] = (a10 + a11) * inv;
}

// ---------------- K3: gi += ctx · W_ih[:, E:]^T  (4-wave k-split) ----------
__global__ __launch_bounds__(256) void k_gru_ctx(const float* __restrict__ W_ih,
                                                 float* __restrict__ ws) {
    int blk = blockIdx.x, tid = threadIdx.x;
    __shared__ float redmv[4][64][16];
    int wave = tid >> 6, lane = tid & 63;
    int m = lane & 31, khalf = lane >> 5;
    int n = blk * 32 + m;
    const float* aptr = ws + WS_CTX + (size_t)m * H + khalf * 8;
    const float* bptr = W_ih + (size_t)n * S + E + khalf * 8;
    f32x16_t acc = {};
    for (int k0 = wave * 128; k0 < wave * 128 + 128; k0 += 16)
        acc = __builtin_amdgcn_mfma_f32_32x32x16_bf16(cvt8(aptr + k0),
                                                      cvt8(bptr + k0), acc, 0, 0, 0);
#pragma unroll
    for (int r = 0; r < 16; ++r) redmv[wave][lane][r] = acc[r];
    __syncthreads();
    if (wave == 0) {
#pragma unroll
        for (int r = 0; r < 16; ++r) {
            float v = redmv[0][lane][r] + redmv[1][lane][r] +
                      redmv[2][lane][r] + redmv[3][lane][r];
            int row = (r & 3) + 8 * (r >> 2) + 4 * khalf;
            ws[WS_GI + row * G3 + n] += v;
        }
    }
}

// ---------------- K4: GRU pointwise; emits fp32 st and bf16 st -------------
__global__ __launch_bounds__(256) void k_combine(const float* __restrict__ emb,
                                                 const float* __restrict__ last_hidden,
                                                 float* __restrict__ ws,
                                                 unsigned short* __restrict__ bf,
                                                 float* __restrict__ out) {
    int i = blockIdx.x * 256 + threadIdx.x;
    int b = i >> 9, h = i & 511;
    float gi_r = ws[WS_GI + b * G3 + h];
    float gi_z = ws[WS_GI + b * G3 + H + h];
    float gi_n = ws[WS_GI + b * G3 + 2 * H + h];
    float gh_r = ws[WS_GH + b * G3 + h];
    float gh_z = ws[WS_GH + b * G3 + H + h];
    float gh_n = ws[WS_GH + b * G3 + 2 * H + h];
    float rr = 1.f / (1.f + __expf(-(gi_r + gh_r)));
    float zz = 1.f / (1.f + __expf(-(gi_z + gh_z)));
    float nn = fast_tanh(gi_n + rr * gh_n);
    float hp = last_hidden[b * H + h];
    float hn = (1.f - zz) * nn + zz * hp;
    out[V * B + b * H + h] = hn;
    out[V * B + B * H + b * H + h] = hn;
    ws[WS_ST + b * S + h] = hn;
    bf[BF_ST + b * S + h] = f2bf(hn);
    if (h < E) {
        float ev = emb[b * E + h];
        ws[WS_ST + b * S + H + h] = ev;
        bf[BF_ST + b * S + H + h] = f2bf(ev);
    }
}

// ---------------- K5: logits = copy-reduce (blk<576) + score_g (k-split) ---
__global__ __launch_bounds__(256) void k_logits(const unsigned short* __restrict__ bf,
                                                const float* __restrict__ W_gen,
                                                const float* __restrict__ b_gen,
                                                float* __restrict__ ws) {
    int blk = blockIdx.x, tid = threadIdx.x;
    __shared__ float shmem[4 * 64 * 16];        // 16 KB (st_s uses first 640)
    int wave = tid >> 6, lane = tid & 63;
    if (blk < 576) {
        // copy scores: tanh-matrix · st
        int b = blk / 18, t0 = (blk % 18) * 16;
        float* st_s = shmem;
        for (int i = tid; i < S; i += 256) st_s[i] = ws[WS_ST + b * S + i];
        __syncthreads();
#pragma unroll
        for (int tl = 0; tl < 4; ++tl) {
            int t = t0 + wave * 4 + tl;
            const unsigned short* row = bf + BF_TANH + ((size_t)b * TENC + t) * S;
            float acc = 0.f;
#pragma unroll
            for (int i = 0; i < 10; ++i) {
                int s = lane + 64 * i;
                acc += bf2f(row[s]) * st_s[s];
            }
            for (int off = 32; off > 0; off >>= 1) acc += __shfl_down(acc, off, 64);
            if (lane == 0) ws[WS_LOGIT + (size_t)b * NLOG + V + t] = acc;
        }
    } else {
        // score_g: st · W_gen^T, 4-wave k-split (K=640, 160/wave)
        float (*redmv)[64][16] = (float (*)[64][16])shmem;
        int m = lane & 31, khalf = lane >> 5;
        int n = (blk - 576) * 32 + m;
        int nr = (n < V) ? n : (V - 1);
        const unsigned short* aptr = bf + BF_ST + (size_t)m * S + khalf * 8;
        const float* bptr = W_gen + (size_t)nr * S + khalf * 8;
        f32x16_t acc = {};
        for (int k0 = wave * 160; k0 < wave * 160 + 160; k0 += 16)
            acc = __builtin_amdgcn_mfma_f32_32x32x16_bf16(*(const bf16x8_t*)(aptr + k0),
                                                          cvt8(bptr + k0), acc, 0, 0, 0);
#pragma unroll
        for (int r = 0; r < 16; ++r) redmv[wave][lane][r] = acc[r];
        __syncthreads();
        if (wave == 0 && n < V) {
            float bg = b_gen[n];
#pragma unroll
            for (int r = 0; r < 16; ++r) {
                float v = redmv[0][lane][r] + redmv[1][lane][r] +
                          redmv[2][lane][r] + redmv[3][lane][r];
                int row = (r & 3) + 8 * (r >> 2) + 4 * khalf;
                ws[WS_LOGIT + (size_t)row * NLOG + n] = v + bg;
            }
        }
    }
}

// ---------------- K6: final softmax + one-hot scatter (LDS exp cache) ------
__global__ __launch_bounds__(512) void k_softmax_scatter(const int* __restrict__ u_in,
                                                         const int* __restrict__ m_in,
                                                         float* __restrict__ ws,
                                                         float* __restrict__ out) {
    int b = blockIdx.x, tid = threadIdx.x;
    __shared__ float red1[8], red2[8];
    __shared__ float ex[NLOG];          // 41.2 KB: single global read of logits
    const float* lg = ws + WS_LOGIT + (size_t)b * NLOG;
    float mx = -1e30f;
    for (int i = tid; i < NLOG; i += 512) {
        float v = lg[i];
        ex[i] = v;
        mx = fmaxf(mx, v);
    }
    int lane = tid & 63, wv = tid >> 6;
    for (int off = 32; off > 0; off >>= 1) mx = fmaxf(mx, __shfl_down(mx, off, 64));
    if (lane == 0) red1[wv] = mx;
    __syncthreads();
    mx = red1[0];
#pragma unroll
    for (int w = 1; w < 8; ++w) mx = fmaxf(mx, red1[w]);
    float sm = 0.f;
    for (int i = tid; i < NLOG; i += 512) {
        float e = __expf(ex[i] - mx);
        ex[i] = e;
        sm += e;
    }
    for (int off = 32; off > 0; off >>= 1) sm += __shfl_down(sm, off, 64);
    if (lane == 0) red2[wv] = sm;
    __syncthreads();
    sm = red2[0];
#pragma unroll
    for (int w = 1; w < 8; ++w) sm += red2[w];
    float inv = 1.f / sm;
    for (int i = tid; i < V; i += 512) out[b * V + i] = ex[i] * inv;
    __syncthreads();
    if (tid < TU + TM) {
        int idx = (tid < TU) ? u_in[b * TU + tid] : m_in[b * TM + (tid - TU)];
        atomicAdd(&out[(size_t)b * V + idx], ex[V + tid] * inv);
    } else if (tid < TENC) {
        ws[WS_PCOPY + b * TENC + tid] = ex[V + tid] * inv;   // TZ slice for k_pv
    }
}

// ---------------- K7: dense pv_z_prob accumulation -------------------------
__global__ __launch_bounds__(256) void k_pv(const float* __restrict__ pvp,
                                            const float* __restrict__ ws,
                                            float* __restrict__ out) {
    int b = blockIdx.y;
    int v = blockIdx.x * 256 + threadIdx.x;
    __shared__ float p[TZ];
    if (threadIdx.x < TZ) p[threadIdx.x] = ws[WS_PCOPY + b * TENC + TU + TM + threadIdx.x];
    __syncthreads();
    if (v >= V) return;
    float acc = 0.f;
#pragma unroll 4
    for (int t = 0; t < TZ; ++t) acc += p[t] * pvp[((size_t)b * TZ + t) * V + v];
    out[(size_t)b * V + v] += acc;
}

extern "C" void kernel_launch(void* const* d_in, const int* in_sizes, int n_in,
                              void* d_out, int out_size, void* d_ws, size_t ws_size,
                              hipStream_t stream) {
    const int*   u_input   = (const int*)d_in[0];
    const float* u_h       = (const float*)d_in[2];
    const int*   m_input   = (const int*)d_in[3];
    const float* m_h       = (const float*)d_in[5];
    const float* pv_prob   = (const float*)d_in[6];
    const float* pz_h      = (const float*)d_in[7];
    const float* emb       = (const float*)d_in[9];
    const float* last_h    = (const float*)d_in[10];
    const float* W_attn    = (const float*)d_in[11];
    const float* b_attn    = (const float*)d_in[12];
    const float* v_attn    = (const float*)d_in[13];
    const float* W_ih      = (const float*)d_in[14];
    const float* W_hh      = (const float*)d_in[15];
    const float* b_ih      = (const float*)d_in[16];
    const float* b_hh      = (const float*)d_in[17];
    const float* W_gen     = (const float*)d_in[18];
    const float* b_gen     = (const float*)d_in[19];
    const float* W_cpu     = (const float*)d_in[20];
    const float* b_cpu     = (const float*)d_in[21];
    const float* W_cpm     = (const float*)d_in[22];
    const float* b_cpm     = (const float*)d_in[23];
    const float* W_cppz    = (const float*)d_in[24];
    const float* b_cppz    = (const float*)d_in[25];
    float* ws  = (float*)d_ws;
    unsigned short* bf = (unsigned short*)(ws + WS_F_TOTAL);
    float* out = (float*)d_out;

    hipLaunchKernelGGL(k_prep, dim3(NMV + CVT_ALL / 256), dim3(256), 0, stream,
                       W_attn, W_cpu, W_cpm, W_cppz, u_h, m_h, pz_h,
                       last_h, emb, W_hh, W_ih, b_attn, b_hh, b_ih, ws, bf);
    hipLaunchKernelGGL(k_enc_mfma, dim3(576), dim3(256), 0, stream,
                       bf, v_attn, b_cpu, b_cpm, b_cppz, ws, bf);
    hipLaunchKernelGGL(k_softmax_ctx, dim3(B), dim3(256), 0, stream, bf, ws);
    hipLaunchKernelGGL(k_gru_ctx, dim3(48), dim3(256), 0, stream, W_ih, ws);
    hipLaunchKernelGGL(k_combine, dim3(64), dim3(256), 0, stream, emb, last_h, ws, bf, out);
    hipLaunchKernelGGL(k_logits, dim3(576 + 313), dim3(256), 0, stream, bf, W_gen, b_gen, ws);
    hipLaunchKernelGGL(k_softmax_scatter, dim3(B), dim3(512), 0, stream,
                       u_input, m_input, ws, out);
    hipLaunchKernelGGL(k_pv, dim3(40, B), dim3(256), 0, stream, pv_prob, ws, out);
}

// Round 6
// 455.238 us; speedup vs baseline: 1.1270x; 1.0283x over previous
//
#include <hip/hip_runtime.h>
#include <math.h>

// Problem constants
#define B   32
#define TU  128
#define TM  128
#define TZ  32
#define TENC 288
#define V   10000
#define H   512
#define E   128
#define S   640          // E + H
#define G3  1536         // 3*H
#define NLOG (V + TENC)  // 10288

// Workspace float region (float offsets)
#define WS_Q      0                       // B*H
#define WS_SCORE  (WS_Q + B*H)            // B*TENC
#define WS_CTX    (WS_SCORE + B*TENC)     // B*H
#define WS_GI     (WS_CTX + B*H)          // B*G3
#define WS_GH     (WS_GI + B*G3)          // B*G3
#define WS_ST     (WS_GH + B*G3)          // B*S
#define WS_LOGIT  (WS_ST + B*S)           // B*NLOG
#define WS_PCOPY  (WS_LOGIT + B*NLOG)     // B*TENC
#define WS_F_TOTAL (WS_PCOPY + B*TENC)    // 499200 floats (16B-aligned)

// bf16 (ushort) region, offsets from bf = (ushort*)(ws + WS_F_TOTAL).
#define BF_WA2  0                         // W_attn[:,H:] 16 tiles x 512 x 32
#define BF_WCP  (BF_WA2 + 512*512)        // 3 segs, each 16 tiles x 640 x 32
#define BF_ENC  (BF_WCP + 3*640*512)      // [b][k/32][t 288][32]
#define BF_ST   (BF_ENC + B*TENC*H)       // [b][s 640]
#define BF_TANH (BF_ST + B*S)             // [b][t 288][s 640] tanh(enc·Wcp+b)

typedef __attribute__((ext_vector_type(8))) short bf16x8_t;
typedef __attribute__((ext_vector_type(4))) float f32x4_t;
typedef __attribute__((ext_vector_type(16))) float f32x16_t;

__device__ __forceinline__ float fast_tanh(float x) {
    return 1.f - 2.f / (__expf(2.f * x) + 1.f);
}

__device__ __forceinline__ unsigned short f2bf(float x) {
    unsigned int u = __float_as_uint(x);
    u += 0x7fffu + ((u >> 16) & 1u);   // RNE
    return (unsigned short)(u >> 16);
}

__device__ __forceinline__ float bf2f(unsigned short u) {
    return __uint_as_float(((unsigned int)u) << 16);
}

__device__ __forceinline__ bf16x8_t cvt8(const float* p) {
    float4 a = *(const float4*)(p);
    float4 b = *(const float4*)(p + 4);
    bf16x8_t r;
    r[0] = (short)f2bf(a.x); r[1] = (short)f2bf(a.y);
    r[2] = (short)f2bf(a.z); r[3] = (short)f2bf(a.w);
    r[4] = (short)f2bf(b.x); r[5] = (short)f2bf(b.y);
    r[6] = (short)f2bf(b.z); r[7] = (short)f2bf(b.w);
    return r;
}

__device__ __forceinline__ const float* enc_row(const float* u, const float* m,
                                                const float* pz, int b, int t) {
    if (t < TU) return u + ((size_t)b * TU + t) * H;
    if (t < TU + TM) return m + ((size_t)b * TM + (t - TU)) * H;
    return pz + ((size_t)b * TZ + (t - TU - TM)) * H;
}

// ---------------- K0: prep = matvec(q, gh, gi_emb) + all cvt ---------------
#define CVT_WA2_END  65536                      // 512 g x 128 float4 units
#define CVT_TOTAL    (CVT_WA2_END + 3*81920)    // 311296
#define CVTE_TOTAL   (B * TENC * 128)           // 1179648 float4 units
#define CVT_ALL      (CVT_TOTAL + CVTE_TOTAL)
#define NMV          112
__global__ __launch_bounds__(256) void k_prep(const float* __restrict__ W_attn,
                                              const float* __restrict__ W_cpu,
                                              const float* __restrict__ W_cpm,
                                              const float* __restrict__ W_cppz,
                                              const float* __restrict__ u_h,
                                              const float* __restrict__ m_h,
                                              const float* __restrict__ pz_h,
                                              const float* __restrict__ last_h,
                                              const float* __restrict__ emb,
                                              const float* __restrict__ W_hh,
                                              const float* __restrict__ W_ih,
                                              const float* __restrict__ b_attn,
                                              const float* __restrict__ b_hh,
                                              const float* __restrict__ b_ih,
                                              float* __restrict__ ws,
                                              unsigned short* __restrict__ bf) {
    int blk = blockIdx.x, tid = threadIdx.x;
    __shared__ float redmv[4][64][16];          // 16 KB
    if (blk < NMV) {
        int wave = tid >> 6, lane = tid & 63;
        int m = lane & 31, khalf = lane >> 5;
        f32x16_t acc = {};
        int n;
        if (blk < 16) {                         // q: K=512
            n = blk * 32 + m;
            const float* aptr = last_h + (size_t)m * H + khalf * 8;
            const float* bptr = W_attn + (size_t)n * 1024 + khalf * 8;
            for (int k0 = wave * 128; k0 < wave * 128 + 128; k0 += 16)
                acc = __builtin_amdgcn_mfma_f32_32x32x16_bf16(cvt8(aptr + k0),
                                                              cvt8(bptr + k0), acc, 0, 0, 0);
        } else if (blk < 64) {                  // gh: K=512
            n = (blk - 16) * 32 + m;
            const float* aptr = last_h + (size_t)m * H + khalf * 8;
            const float* bptr = W_hh + (size_t)n * H + khalf * 8;
            for (int k0 = wave * 128; k0 < wave * 128 + 128; k0 += 16)
                acc = __builtin_amdgcn_mfma_f32_32x32x16_bf16(cvt8(aptr + k0),
                                                              cvt8(bptr + k0), acc, 0, 0, 0);
        } else {                                // gi emb-part: K=128
            n = (blk - 64) * 32 + m;
            const float* aptr = emb + (size_t)m * E + khalf * 8;
            const float* bptr = W_ih + (size_t)n * S + khalf * 8;
            for (int k0 = wave * 32; k0 < wave * 32 + 32; k0 += 16)
                acc = __builtin_amdgcn_mfma_f32_32x32x16_bf16(cvt8(aptr + k0),
                                                              cvt8(bptr + k0), acc, 0, 0, 0);
        }
#pragma unroll
        for (int r = 0; r < 16; ++r) redmv[wave][lane][r] = acc[r];
        __syncthreads();
        if (wave == 0) {
#pragma unroll
            for (int r = 0; r < 16; ++r) {
                float v = redmv[0][lane][r] + redmv[1][lane][r] +
                          redmv[2][lane][r] + redmv[3][lane][r];
                int row = (r & 3) + 8 * (r >> 2) + 4 * khalf;   // b index
                if (blk < 16)      ws[WS_Q  + row * H  + n] = v + b_attn[n];
                else if (blk < 64) ws[WS_GH + row * G3 + n] = v + b_hh[n];
                else               ws[WS_GI + row * G3 + n] = v + b_ih[n];
            }
        }
        return;
    }
    int idx = (blk - NMV) * 256 + tid;
    if (idx >= CVT_ALL) return;
    const float* src;
    unsigned short* dst;
    if (idx < CVT_WA2_END) {
        int g = idx >> 7, c4 = idx & 127;
        int k = c4 * 4, kt = k >> 5, kin = k & 31;
        src = W_attn + (size_t)g * 1024 + 512 + k;
        dst = bf + BF_WA2 + kt * (512 * 32) + g * 32 + kin;
    } else if (idx < CVT_TOTAL) {
        int r = idx - CVT_WA2_END;
        int seg = r / 81920, q = r % 81920;
        int s = q >> 7, c4 = q & 127;
        int k = c4 * 4, kt = k >> 5, kin = k & 31;
        const float* s0 = (seg == 0) ? W_cpu : (seg == 1) ? W_cpm : W_cppz;
        src = s0 + (size_t)s * 512 + k;
        dst = bf + BF_WCP + seg * 327680 + kt * (640 * 32) + s * 32 + kin;
    } else {
        int e = idx - CVT_TOTAL;
        int b = e / (TENC * 128);
        int r = e % (TENC * 128);
        int t = r >> 7, c4 = r & 127;
        int k = c4 * 4, kt = k >> 5, kin = k & 31;
        src = enc_row(u_h, m_h, pz_h, b, t) + k;
        dst = bf + BF_ENC + (((size_t)b * 16 + kt) * TENC + t) * 32 + kin;
    }
    float4 v = *(const float4*)src;
    ushort4 o;
    o.x = f2bf(v.x); o.y = f2bf(v.y); o.z = f2bf(v.z); o.w = f2bf(v.w);
    *(ushort4*)dst = o;
}

// ---------------- K1: enc MFMA, LDS staging + T14 async-stage split --------
// Per kt: ISSUE next tile's 9-11 independent 16B global loads into regs
// BEFORE the current tile's MFMAs; after the post-compute barrier, drain
// (vmcnt) and ds_write. Hides the ~200-300cy L2 stage latency under the
// ~200cy ds_read+MFMA phase instead of serializing (was: stage -> barrier
// -> compute -> barrier every kt, stage latency fully on critical path).
__global__ __launch_bounds__(256) void k_enc_mfma(const unsigned short* __restrict__ bf,
                                                  const float* __restrict__ v_attn,
                                                  const float* __restrict__ b_cpu,
                                                  const float* __restrict__ b_cpm,
                                                  const float* __restrict__ b_cppz,
                                                  float* __restrict__ ws,
                                                  unsigned short* __restrict__ bft) {
    __shared__ __attribute__((aligned(16))) unsigned short lds_w[640 * 32]; // 40 KB
    __shared__ __attribute__((aligned(16))) unsigned short lds_a[32 * 32];  // 2 KB
    __shared__ float red[4][32];
    int blk = blockIdx.x;
    int typeC = (blk >= 288);
    int idx = typeC ? blk - 288 : blk;
    int b = idx / 9, t0 = (idx % 9) * 32;            // 9*32 = 288 = TENC
    int tid = threadIdx.x, wave = tid >> 6, lane = tid & 63;
    int n16 = lane & 15, quad = lane >> 4;
    const unsigned short* asrc0 =
        bf + BF_ENC + (((size_t)b * 16) * TENC + t0) * 32;   // + kt*TENC*32
    if (!typeC) {
        // ---- attn: 512 cols, wave w owns groups w*8..w*8+7 ----
        bf16x8_t rw0, rw1, rw2, rw3, rw4, rw5, rw6, rw7, ra;
        const unsigned short* wb = bf + BF_WA2;
        // prologue: stage kt=0
        rw0 = *(const bf16x8_t*)&wb[(0 * 256 + tid) * 8];
        rw1 = *(const bf16x8_t*)&wb[(1 * 256 + tid) * 8];
        rw2 = *(const bf16x8_t*)&wb[(2 * 256 + tid) * 8];
        rw3 = *(const bf16x8_t*)&wb[(3 * 256 + tid) * 8];
        rw4 = *(const bf16x8_t*)&wb[(4 * 256 + tid) * 8];
        rw5 = *(const bf16x8_t*)&wb[(5 * 256 + tid) * 8];
        rw6 = *(const bf16x8_t*)&wb[(6 * 256 + tid) * 8];
        rw7 = *(const bf16x8_t*)&wb[(7 * 256 + tid) * 8];
        if (tid < 128) ra = *(const bf16x8_t*)&asrc0[tid * 8];
        *(bf16x8_t*)&lds_w[(0 * 256 + tid) * 8] = rw0;
        *(bf16x8_t*)&lds_w[(1 * 256 + tid) * 8] = rw1;
        *(bf16x8_t*)&lds_w[(2 * 256 + tid) * 8] = rw2;
        *(bf16x8_t*)&lds_w[(3 * 256 + tid) * 8] = rw3;
        *(bf16x8_t*)&lds_w[(4 * 256 + tid) * 8] = rw4;
        *(bf16x8_t*)&lds_w[(5 * 256 + tid) * 8] = rw5;
        *(bf16x8_t*)&lds_w[(6 * 256 + tid) * 8] = rw6;
        *(bf16x8_t*)&lds_w[(7 * 256 + tid) * 8] = rw7;
        if (tid < 128) *(bf16x8_t*)&lds_a[tid * 8] = ra;
        __syncthreads();
        f32x4_t acc[2][8];
#pragma unroll
        for (int tl = 0; tl < 2; ++tl)
#pragma unroll
            for (int j = 0; j < 8; ++j) acc[tl][j] = (f32x4_t){0.f, 0.f, 0.f, 0.f};
        for (int kt = 0; kt < 16; ++kt) {
            if (kt < 15) {      // issue next tile's loads (no wait)
                const unsigned short* wsrc = wb + (size_t)(kt + 1) * (512 * 32);
                rw0 = *(const bf16x8_t*)&wsrc[(0 * 256 + tid) * 8];
                rw1 = *(const bf16x8_t*)&wsrc[(1 * 256 + tid) * 8];
                rw2 = *(const bf16x8_t*)&wsrc[(2 * 256 + tid) * 8];
                rw3 = *(const bf16x8_t*)&wsrc[(3 * 256 + tid) * 8];
                rw4 = *(const bf16x8_t*)&wsrc[(4 * 256 + tid) * 8];
                rw5 = *(const bf16x8_t*)&wsrc[(5 * 256 + tid) * 8];
                rw6 = *(const bf16x8_t*)&wsrc[(6 * 256 + tid) * 8];
                rw7 = *(const bf16x8_t*)&wsrc[(7 * 256 + tid) * 8];
                if (tid < 128)
                    ra = *(const bf16x8_t*)&asrc0[(size_t)(kt + 1) * TENC * 32 + tid * 8];
            }
            bf16x8_t a0 = *(const bf16x8_t*)&lds_a[n16 * 32 + quad * 8];
            bf16x8_t a1 = *(const bf16x8_t*)&lds_a[(n16 + 16) * 32 + quad * 8];
#pragma unroll
            for (int j = 0; j < 8; ++j) {
                bf16x8_t bb = *(const bf16x8_t*)
                    &lds_w[((wave * 8 + j) * 16 + n16) * 32 + quad * 8];
                acc[0][j] = __builtin_amdgcn_mfma_f32_16x16x32_bf16(a0, bb, acc[0][j], 0, 0, 0);
                acc[1][j] = __builtin_amdgcn_mfma_f32_16x16x32_bf16(a1, bb, acc[1][j], 0, 0, 0);
            }
            __syncthreads();
            if (kt < 15) {      // write-late: vmcnt drain happens here
                *(bf16x8_t*)&lds_w[(0 * 256 + tid) * 8] = rw0;
                *(bf16x8_t*)&lds_w[(1 * 256 + tid) * 8] = rw1;
                *(bf16x8_t*)&lds_w[(2 * 256 + tid) * 8] = rw2;
                *(bf16x8_t*)&lds_w[(3 * 256 + tid) * 8] = rw3;
                *(bf16x8_t*)&lds_w[(4 * 256 + tid) * 8] = rw4;
                *(bf16x8_t*)&lds_w[(5 * 256 + tid) * 8] = rw5;
                *(bf16x8_t*)&lds_w[(6 * 256 + tid) * 8] = rw6;
                *(bf16x8_t*)&lds_w[(7 * 256 + tid) * 8] = rw7;
                if (tid < 128) *(bf16x8_t*)&lds_a[tid * 8] = ra;
            }
            __syncthreads();
        }
        float sval[2][4] = {{0.f, 0.f, 0.f, 0.f}, {0.f, 0.f, 0.f, 0.f}};
#pragma unroll
        for (int j = 0; j < 8; ++j) {
            int g = (wave * 8 + j) * 16 + n16;
            float q = ws[WS_Q + b * H + g];
            float va = v_attn[g];
#pragma unroll
            for (int tl = 0; tl < 2; ++tl)
#pragma unroll
                for (int r = 0; r < 4; ++r)
                    sval[tl][r] += fast_tanh(acc[tl][j][r] + q) * va;
        }
#pragma unroll
        for (int tl = 0; tl < 2; ++tl)
#pragma unroll
            for (int r = 0; r < 4; ++r)
#pragma unroll
                for (int off = 8; off > 0; off >>= 1)
                    sval[tl][r] += __shfl_down(sval[tl][r], off, 64);
        if (n16 == 0)
#pragma unroll
            for (int tl = 0; tl < 2; ++tl)
#pragma unroll
                for (int r = 0; r < 4; ++r)
                    red[wave][tl * 16 + quad * 4 + r] = sval[tl][r];
        __syncthreads();
        if (tid < 32)
            ws[WS_SCORE + b * TENC + t0 + tid] =
                red[0][tid] + red[1][tid] + red[2][tid] + red[3][tid];
    } else {
        // ---- copy: 640 cols, wave w owns groups w*10..w*10+9 ----
        int seg = (t0 < TU) ? 0 : (t0 < TU + TM) ? 1 : 2;
        const float* bias = (seg == 0) ? b_cpu : (seg == 1) ? b_cpm : b_cppz;
        const unsigned short* wb = bf + BF_WCP + seg * 327680;
        bf16x8_t rw0, rw1, rw2, rw3, rw4, rw5, rw6, rw7, rw8, rw9, ra;
        rw0 = *(const bf16x8_t*)&wb[(0 * 256 + tid) * 8];
        rw1 = *(const bf16x8_t*)&wb[(1 * 256 + tid) * 8];
        rw2 = *(const bf16x8_t*)&wb[(2 * 256 + tid) * 8];
        rw3 = *(const bf16x8_t*)&wb[(3 * 256 + tid) * 8];
        rw4 = *(const bf16x8_t*)&wb[(4 * 256 + tid) * 8];
        rw5 = *(const bf16x8_t*)&wb[(5 * 256 + tid) * 8];
        rw6 = *(const bf16x8_t*)&wb[(6 * 256 + tid) * 8];
        rw7 = *(const bf16x8_t*)&wb[(7 * 256 + tid) * 8];
        rw8 = *(const bf16x8_t*)&wb[(8 * 256 + tid) * 8];
        rw9 = *(const bf16x8_t*)&wb[(9 * 256 + tid) * 8];
        if (tid < 128) ra = *(const bf16x8_t*)&asrc0[tid * 8];
        *(bf16x8_t*)&lds_w[(0 * 256 + tid) * 8] = rw0;
        *(bf16x8_t*)&lds_w[(1 * 256 + tid) * 8] = rw1;
        *(bf16x8_t*)&lds_w[(2 * 256 + tid) * 8] = rw2;
        *(bf16x8_t*)&lds_w[(3 * 256 + tid) * 8] = rw3;
        *(bf16x8_t*)&lds_w[(4 * 256 + tid) * 8] = rw4;
        *(bf16x8_t*)&lds_w[(5 * 256 + tid) * 8] = rw5;
        *(bf16x8_t*)&lds_w[(6 * 256 + tid) * 8] = rw6;
        *(bf16x8_t*)&lds_w[(7 * 256 + tid) * 8] = rw7;
        *(bf16x8_t*)&lds_w[(8 * 256 + tid) * 8] = rw8;
        *(bf16x8_t*)&lds_w[(9 * 256 + tid) * 8] = rw9;
        if (tid < 128) *(bf16x8_t*)&lds_a[tid * 8] = ra;
        __syncthreads();
        f32x4_t acc[2][10];
#pragma unroll
        for (int tl = 0; tl < 2; ++tl)
#pragma unroll
            for (int j = 0; j < 10; ++j) acc[tl][j] = (f32x4_t){0.f, 0.f, 0.f, 0.f};
        for (int kt = 0; kt < 16; ++kt) {
            if (kt < 15) {
                const unsigned short* wsrc = wb + (size_t)(kt + 1) * (640 * 32);
                rw0 = *(const bf16x8_t*)&wsrc[(0 * 256 + tid) * 8];
                rw1 = *(const bf16x8_t*)&wsrc[(1 * 256 + tid) * 8];
                rw2 = *(const bf16x8_t*)&wsrc[(2 * 256 + tid) * 8];
                rw3 = *(const bf16x8_t*)&wsrc[(3 * 256 + tid) * 8];
                rw4 = *(const bf16x8_t*)&wsrc[(4 * 256 + tid) * 8];
                rw5 = *(const bf16x8_t*)&wsrc[(5 * 256 + tid) * 8];
                rw6 = *(const bf16x8_t*)&wsrc[(6 * 256 + tid) * 8];
                rw7 = *(const bf16x8_t*)&wsrc[(7 * 256 + tid) * 8];
                rw8 = *(const bf16x8_t*)&wsrc[(8 * 256 + tid) * 8];
                rw9 = *(const bf16x8_t*)&wsrc[(9 * 256 + tid) * 8];
                if (tid < 128)
                    ra = *(const bf16x8_t*)&asrc0[(size_t)(kt + 1) * TENC * 32 + tid * 8];
            }
            bf16x8_t a0 = *(const bf16x8_t*)&lds_a[n16 * 32 + quad * 8];
            bf16x8_t a1 = *(const bf16x8_t*)&lds_a[(n16 + 16) * 32 + quad * 8];
#pragma unroll
            for (int j = 0; j < 10; ++j) {
                bf16x8_t bb = *(const bf16x8_t*)
                    &lds_w[((wave * 10 + j) * 16 + n16) * 32 + quad * 8];
                acc[0][j] = __builtin_amdgcn_mfma_f32_16x16x32_bf16(a0, bb, acc[0][j], 0, 0, 0);
                acc[1][j] = __builtin_amdgcn_mfma_f32_16x16x32_bf16(a1, bb, acc[1][j], 0, 0, 0);
            }
            __syncthreads();
            if (kt < 15) {
                *(bf16x8_t*)&lds_w[(0 * 256 + tid) * 8] = rw0;
                *(bf16x8_t*)&lds_w[(1 * 256 + tid) * 8] = rw1;
                *(bf16x8_t*)&lds_w[(2 * 256 + tid) * 8] = rw2;
                *(bf16x8_t*)&lds_w[(3 * 256 + tid) * 8] = rw3;
                *(bf16x8_t*)&lds_w[(4 * 256 + tid) * 8] = rw4;
                *(bf16x8_t*)&lds_w[(5 * 256 + tid) * 8] = rw5;
                *(bf16x8_t*)&lds_w[(6 * 256 + tid) * 8] = rw6;
                *(bf16x8_t*)&lds_w[(7 * 256 + tid) * 8] = rw7;
                *(bf16x8_t*)&lds_w[(8 * 256 + tid) * 8] = rw8;
                *(bf16x8_t*)&lds_w[(9 * 256 + tid) * 8] = rw9;
                if (tid < 128) *(bf16x8_t*)&lds_a[tid * 8] = ra;
            }
            __syncthreads();
        }
#pragma unroll
        for (int j = 0; j < 10; ++j) {
            int s = (wave * 10 + j) * 16 + n16;
            float bi = bias[s];
#pragma unroll
            for (int tl = 0; tl < 2; ++tl)
#pragma unroll
                for (int r = 0; r < 4; ++r) {
                    int t = t0 + tl * 16 + quad * 4 + r;
                    bft[BF_TANH + ((size_t)b * TENC + t) * S + s] =
                        f2bf(fast_tanh(acc[tl][j][r] + bi));
                }
        }
    }
}

// ---------------- K2: softmax over t and context (ushort2, 2 h/thread) -----
__global__ __launch_bounds__(256) void k_softmax_ctx(const unsigned short* __restrict__ bf,
                                                     float* __restrict__ ws) {
    int b = blockIdx.x, tid = threadIdx.x;
    __shared__ float wsm[TENC];
    __shared__ float red1[4], red2[4];
    float local = -1e30f;
    for (int t = tid; t < TENC; t += 256) {
        float s = ws[WS_SCORE + b * TENC + t];
        wsm[t] = s;
        local = fmaxf(local, s);
    }
    int lane = tid & 63, wv = tid >> 6;
    for (int off = 32; off > 0; off >>= 1) local = fmaxf(local, __shfl_down(local, off, 64));
    if (lane == 0) red1[wv] = local;
    __syncthreads();
    float mx = fmaxf(fmaxf(red1[0], red1[1]), fmaxf(red1[2], red1[3]));
    float ls = 0.f;
    for (int t = tid; t < TENC; t += 256) {
        float e = __expf(wsm[t] - mx);
        wsm[t] = e;
        ls += e;
    }
    for (int off = 32; off > 0; off >>= 1) ls += __shfl_down(ls, off, 64);
    if (lane == 0) red2[wv] = ls;
    __syncthreads();
    float inv = 1.f / (red2[0] + red2[1] + red2[2] + red2[3]);

    int h2 = tid * 2;
    int kt = h2 >> 5, hin = h2 & 31;
    const unsigned short* ep = bf + BF_ENC + ((size_t)b * 16 + kt) * TENC * 32 + hin;
    float a00 = 0.f, a01 = 0.f, a10 = 0.f, a11 = 0.f;
#pragma unroll 2
    for (int t = 0; t < TENC; t += 2) {
        ushort2 v0 = *(const ushort2*)(ep + (size_t)t * 32);
        ushort2 v1 = *(const ushort2*)(ep + (size_t)(t + 1) * 32);
        float w0 = wsm[t], w1 = wsm[t + 1];
        a00 += w0 * bf2f(v0.x); a10 += w0 * bf2f(v0.y);
        a01 += w1 * bf2f(v1.x); a11 += w1 * bf2f(v1.y);
    }
    ws[WS_CTX + b * H + h2]     = (a00 + a01) * inv;
    ws[WS_CTX + b * H + h2 + 1] = (a10 + a11) * inv;
}

// ---------------- K3: gi += ctx · W_ih[:, E:]^T  (4-wave k-split) ----------
__global__ __launch_bounds__(256) void k_gru_ctx(const float* __restrict__ W_ih,
                                                 float* __restrict__ ws) {
    int blk = blockIdx.x, tid = threadIdx.x;
    __shared__ float redmv[4][64][16];
    int wave = tid >> 6, lane = tid & 63;
    int m = lane & 31, khalf = lane >> 5;
    int n = blk * 32 + m;
    const float* aptr = ws + WS_CTX + (size_t)m * H + khalf * 8;
    const float* bptr = W_ih + (size_t)n * S + E + khalf * 8;
    f32x16_t acc = {};
    for (int k0 = wave * 128; k0 < wave * 128 + 128; k0 += 16)
        acc = __builtin_amdgcn_mfma_f32_32x32x16_bf16(cvt8(aptr + k0),
                                                      cvt8(bptr + k0), acc, 0, 0, 0);
#pragma unroll
    for (int r = 0; r < 16; ++r) redmv[wave][lane][r] = acc[r];
    __syncthreads();
    if (wave == 0) {
#pragma unroll
        for (int r = 0; r < 16; ++r) {
            float v = redmv[0][lane][r] + redmv[1][lane][r] +
                      redmv[2][lane][r] + redmv[3][lane][r];
            int row = (r & 3) + 8 * (r >> 2) + 4 * khalf;
            ws[WS_GI + row * G3 + n] += v;
        }
    }
}

// ---------------- K4: GRU pointwise; emits fp32 st and bf16 st -------------
__global__ __launch_bounds__(256) void k_combine(const float* __restrict__ emb,
                                                 const float* __restrict__ last_hidden,
                                                 float* __restrict__ ws,
                                                 unsigned short* __restrict__ bf,
                                                 float* __restrict__ out) {
    int i = blockIdx.x * 256 + threadIdx.x;
    int b = i >> 9, h = i & 511;
    float gi_r = ws[WS_GI + b * G3 + h];
    float gi_z = ws[WS_GI + b * G3 + H + h];
    float gi_n = ws[WS_GI + b * G3 + 2 * H + h];
    float gh_r = ws[WS_GH + b * G3 + h];
    float gh_z = ws[WS_GH + b * G3 + H + h];
    float gh_n = ws[WS_GH + b * G3 + 2 * H + h];
    float rr = 1.f / (1.f + __expf(-(gi_r + gh_r)));
    float zz = 1.f / (1.f + __expf(-(gi_z + gh_z)));
    float nn = fast_tanh(gi_n + rr * gh_n);
    float hp = last_hidden[b * H + h];
    float hn = (1.f - zz) * nn + zz * hp;
    out[V * B + b * H + h] = hn;
    out[V * B + B * H + b * H + h] = hn;
    ws[WS_ST + b * S + h] = hn;
    bf[BF_ST + b * S + h] = f2bf(hn);
    if (h < E) {
        float ev = emb[b * E + h];
        ws[WS_ST + b * S + H + h] = ev;
        bf[BF_ST + b * S + H + h] = f2bf(ev);
    }
}

// ---------------- K5: logits = copy-reduce (blk<576) + score_g (k-split) ---
__global__ __launch_bounds__(256) void k_logits(const unsigned short* __restrict__ bf,
                                                const float* __restrict__ W_gen,
                                                const float* __restrict__ b_gen,
                                                float* __restrict__ ws) {
    int blk = blockIdx.x, tid = threadIdx.x;
    __shared__ float shmem[4 * 64 * 16];        // 16 KB (st_s uses first 640)
    int wave = tid >> 6, lane = tid & 63;
    if (blk < 576) {
        // copy scores: tanh-matrix · st
        int b = blk / 18, t0 = (blk % 18) * 16;
        float* st_s = shmem;
        for (int i = tid; i < S; i += 256) st_s[i] = ws[WS_ST + b * S + i];
        __syncthreads();
#pragma unroll
        for (int tl = 0; tl < 4; ++tl) {
            int t = t0 + wave * 4 + tl;
            const unsigned short* row = bf + BF_TANH + ((size_t)b * TENC + t) * S;
            float acc = 0.f;
#pragma unroll
            for (int i = 0; i < 10; ++i) {
                int s = lane + 64 * i;
                acc += bf2f(row[s]) * st_s[s];
            }
            for (int off = 32; off > 0; off >>= 1) acc += __shfl_down(acc, off, 64);
            if (lane == 0) ws[WS_LOGIT + (size_t)b * NLOG + V + t] = acc;
        }
    } else {
        // score_g: st · W_gen^T, 4-wave k-split (K=640, 160/wave)
        float (*redmv)[64][16] = (float (*)[64][16])shmem;
        int m = lane & 31, khalf = lane >> 5;
        int n = (blk - 576) * 32 + m;
        int nr = (n < V) ? n : (V - 1);
        const unsigned short* aptr = bf + BF_ST + (size_t)m * S + khalf * 8;
        const float* bptr = W_gen + (size_t)nr * S + khalf * 8;
        f32x16_t acc = {};
        for (int k0 = wave * 160; k0 < wave * 160 + 160; k0 += 16)
            acc = __builtin_amdgcn_mfma_f32_32x32x16_bf16(*(const bf16x8_t*)(aptr + k0),
                                                          cvt8(bptr + k0), acc, 0, 0, 0);
#pragma unroll
        for (int r = 0; r < 16; ++r) redmv[wave][lane][r] = acc[r];
        __syncthreads();
        if (wave == 0 && n < V) {
            float bg = b_gen[n];
#pragma unroll
            for (int r = 0; r < 16; ++r) {
                float v = redmv[0][lane][r] + redmv[1][lane][r] +
                          redmv[2][lane][r] + redmv[3][lane][r];
                int row = (r & 3) + 8 * (r >> 2) + 4 * khalf;
                ws[WS_LOGIT + (size_t)row * NLOG + n] = v + bg;
            }
        }
    }
}

// ---------------- K6: final softmax + one-hot scatter (LDS exp cache) ------
__global__ __launch_bounds__(512) void k_softmax_scatter(const int* __restrict__ u_in,
                                                         const int* __restrict__ m_in,
                                                         float* __restrict__ ws,
                                                         float* __restrict__ out) {
    int b = blockIdx.x, tid = threadIdx.x;
    __shared__ float red1[8], red2[8];
    __shared__ float ex[NLOG];          // 41.2 KB: single global read of logits
    const float* lg = ws + WS_LOGIT + (size_t)b * NLOG;
    float mx = -1e30f;
    for (int i = tid; i < NLOG; i += 512) {
        float v = lg[i];
        ex[i] = v;
        mx = fmaxf(mx, v);
    }
    int lane = tid & 63, wv = tid >> 6;
    for (int off = 32; off > 0; off >>= 1) mx = fmaxf(mx, __shfl_down(mx, off, 64));
    if (lane == 0) red1[wv] = mx;
    __syncthreads();
    mx = red1[0];
#pragma unroll
    for (int w = 1; w < 8; ++w) mx = fmaxf(mx, red1[w]);
    float sm = 0.f;
    for (int i = tid; i < NLOG; i += 512) {
        float e = __expf(ex[i] - mx);
        ex[i] = e;
        sm += e;
    }
    for (int off = 32; off > 0; off >>= 1) sm += __shfl_down(sm, off, 64);
    if (lane == 0) red2[wv] = sm;
    __syncthreads();
    sm = red2[0];
#pragma unroll
    for (int w = 1; w < 8; ++w) sm += red2[w];
    float inv = 1.f / sm;
    for (int i = tid; i < V; i += 512) out[b * V + i] = ex[i] * inv;
    __syncthreads();
    if (tid < TU + TM) {
        int idx = (tid < TU) ? u_in[b * TU + tid] : m_in[b * TM + (tid - TU)];
        atomicAdd(&out[(size_t)b * V + idx], ex[V + tid] * inv);
    } else if (tid < TENC) {
        ws[WS_PCOPY + b * TENC + tid] = ex[V + tid] * inv;   // TZ slice for k_pv
    }
}

// ---------------- K7: dense pv_z_prob accumulation -------------------------
__global__ __launch_bounds__(256) void k_pv(const float* __restrict__ pvp,
                                            const float* __restrict__ ws,
                                            float* __restrict__ out) {
    int b = blockIdx.y;
    int v = blockIdx.x * 256 + threadIdx.x;
    __shared__ float p[TZ];
    if (threadIdx.x < TZ) p[threadIdx.x] = ws[WS_PCOPY + b * TENC + TU + TM + threadIdx.x];
    __syncthreads();
    if (v >= V) return;
    float acc = 0.f;
#pragma unroll 8
    for (int t = 0; t < TZ; ++t) acc += p[t] * pvp[((size_t)b * TZ + t) * V + v];
    out[(size_t)b * V + v] += acc;
}

extern "C" void kernel_launch(void* const* d_in, const int* in_sizes, int n_in,
                              void* d_out, int out_size, void* d_ws, size_t ws_size,
                              hipStream_t stream) {
    const int*   u_input   = (const int*)d_in[0];
    const float* u_h       = (const float*)d_in[2];
    const int*   m_input   = (const int*)d_in[3];
    const float* m_h       = (const float*)d_in[5];
    const float* pv_prob   = (const float*)d_in[6];
    const float* pz_h      = (const float*)d_in[7];
    const float* emb       = (const float*)d_in[9];
    const float* last_h    = (const float*)d_in[10];
    const float* W_attn    = (const float*)d_in[11];
    const float* b_attn    = (const float*)d_in[12];
    const float* v_attn    = (const float*)d_in[13];
    const float* W_ih      = (const float*)d_in[14];
    const float* W_hh      = (const float*)d_in[15];
    const float* b_ih      = (const float*)d_in[16];
    const float* b_hh      = (const float*)d_in[17];
    const float* W_gen     = (const float*)d_in[18];
    const float* b_gen     = (const float*)d_in[19];
    const float* W_cpu     = (const float*)d_in[20];
    const float* b_cpu     = (const float*)d_in[21];
    const float* W_cpm     = (const float*)d_in[22];
    const float* b_cpm     = (const float*)d_in[23];
    const float* W_cppz    = (const float*)d_in[24];
    const float* b_cppz    = (const float*)d_in[25];
    float* ws  = (float*)d_ws;
    unsigned short* bf = (unsigned short*)(ws + WS_F_TOTAL);
    float* out = (float*)d_out;

    hipLaunchKernelGGL(k_prep, dim3(NMV + CVT_ALL / 256), dim3(256), 0, stream,
                       W_attn, W_cpu, W_cpm, W_cppz, u_h, m_h, pz_h,
                       last_h, emb, W_hh, W_ih, b_attn, b_hh, b_ih, ws, bf);
    hipLaunchKernelGGL(k_enc_mfma, dim3(576), dim3(256), 0, stream,
                       bf, v_attn, b_cpu, b_cpm, b_cppz, ws, bf);
    hipLaunchKernelGGL(k_softmax_ctx, dim3(B), dim3(256), 0, stream, bf, ws);
    hipLaunchKernelGGL(k_gru_ctx, dim3(48), dim3(256), 0, stream, W_ih, ws);
    hipLaunchKernelGGL(k_combine, dim3(64), dim3(256), 0, stream, emb, last_h, ws, bf, out);
    hipLaunchKernelGGL(k_logits, dim3(576 + 313), dim3(256), 0, stream, bf, W_gen, b_gen, ws);
    hipLaunchKernelGGL(k_softmax_scatter, dim3(B), dim3(512), 0, stream,
                       u_input, m_input, ws, out);
    hipLaunchKernelGGL(k_pv, dim3(40, B), dim3(256), 0, stream, pv_prob, ws, out);
}